// Round 1
// baseline (53244.452 us; speedup 1.0000x reference)
//
#include <hip/hip_runtime.h>
#include <stdint.h>

#define T_LEN 512
#define H_DIM 512
#define B_TOT 4096
#define GATE_D 514
#define ROWS 16
#define NBLK (B_TOT / ROWS)   // 256

typedef short s16x8 __attribute__((ext_vector_type(8)));
typedef float f32x4 __attribute__((ext_vector_type(4)));

__device__ __forceinline__ ushort f2bf(float f) {
    uint32_t u = __builtin_bit_cast(uint32_t, f);
    u += 0x7FFF + ((u >> 16) & 1);     // RNE
    return (ushort)(u >> 16);
}
__device__ __forceinline__ float bf2f(ushort h) {
    uint32_t u = ((uint32_t)h) << 16;
    return __builtin_bit_cast(float, u);
}
__device__ __forceinline__ float sigmoid_f(float x) {
    return 1.0f / (1.0f + __expf(-x));
}
__device__ __forceinline__ float tanh_f(float x) {
    float ax = fabsf(x);
    float e  = __expf(2.0f * ax);              // inf ok
    float t  = 1.0f - 2.0f / (e + 1.0f);
    return copysignf(t, x);
}

// ---------------- K0: masked mean over time ----------------
__global__ void k_xmean(const float* __restrict__ x, const float* __restrict__ m,
                        float* __restrict__ xmean) {
    int b = blockIdx.x;
    int l = threadIdx.x;
    const float* xr = x + (size_t)b * T_LEN;
    const float* mr = m + (size_t)b * T_LEN;
    float sx = 0.f, sm = 0.f;
    #pragma unroll
    for (int i = 0; i < T_LEN / 64; ++i) {
        float mv = mr[l + i * 64];
        sx += xr[l + i * 64] * mv;
        sm += mv;
    }
    for (int off = 32; off; off >>= 1) {
        sx += __shfl_down(sx, off);
        sm += __shfl_down(sm, off);
    }
    if (l == 0) xmean[b] = sx / sm;
}

// ---------------- K1: pack weights to bf16 MFMA B-fragments ----------------
// Fragment (g_nt, kt): elem[(frag*64 + lane)*8 + j] = W[n][1 + kt*32 + (lane>>4)*8 + j]
// with n = ntl*16 + (lane&15). Columns 0 and 513 (xi, mask) stay fp32 in epilogue.
__global__ void k_pack(const float* __restrict__ Wz, const float* __restrict__ Wr,
                       const float* __restrict__ Wh,
                       ushort* __restrict__ zr, ushort* __restrict__ hh) {
    int bid = blockIdx.x;
    int l = threadIdx.x;
    const float* src;
    ushort* dst;
    int ntl, kt;
    if (bid < 1024) {                 // Wz (g_nt 0..31) then Wr (32..63)
        int g_nt = bid >> 4; kt = bid & 15;
        src = (g_nt < 32) ? Wz : Wr;
        ntl = g_nt & 31;
        dst = zr + ((size_t)bid * 64 + l) * 8;
    } else {
        int id = bid - 1024;          // Wh, nt 0..31
        int nt = id >> 4; kt = id & 15;
        src = Wh; ntl = nt;
        dst = hh + ((size_t)id * 64 + l) * 8;
    }
    int wrow = ntl * 16 + (l & 15);
    int c0 = 1 + kt * 32 + (l >> 4) * 8;
    ushort tmp[8];
    #pragma unroll
    for (int j = 0; j < 8; ++j) tmp[j] = f2bf(src[(size_t)wrow * GATE_D + c0 + j]);
    *(s16x8*)dst = *(s16x8*)tmp;
}

// ---------------- main persistent kernel ----------------
// 256 blocks x 512 threads (8 waves). Each block owns 16 batch rows for all T steps.
// LDS: h (fp32, 32KB) + a_s (bf16 operand buffer reused as hd -> r*hd -> h~, 16KB).
__global__ __launch_bounds__(512, 2) void k_grud(
    const float* __restrict__ x,   const float* __restrict__ xl,
    const float* __restrict__ itv, const float* __restrict__ msk,
    const float* __restrict__ Wgx, const float* __restrict__ bgx,
    const float* __restrict__ Wgh, const float* __restrict__ bgh,
    const float* __restrict__ Wz,  const float* __restrict__ bz,
    const float* __restrict__ Wr,  const float* __restrict__ br,
    const float* __restrict__ Wh,  const float* __restrict__ bh,
    const float* __restrict__ Wo,  const float* __restrict__ bo,
    const float* __restrict__ xmean,
    const ushort* __restrict__ Pzr, const ushort* __restrict__ Phh,
    float* __restrict__ out)
{
    __shared__ float  h_s[ROWS][H_DIM];        // fp32 state (becomes hd in phase A)
    __shared__ ushort a_s[ROWS * H_DIM];       // bf16 operand buffer
    __shared__ float  xi_s[ROWS], mt_s[ROWS], it_s[ROWS];

    const int tid = threadIdx.x;
    const int wv  = tid >> 6;        // 0..7
    const int l   = tid & 63;
    const int r0  = blockIdx.x * ROWS;

    for (int i = tid; i < ROWS * H_DIM; i += 512) ((float*)h_s)[i] = 0.0f;

    const float wgx  = Wgx[0];
    const float bgxv = bgx[0];
    const s16x8* Pzr_v = (const s16x8*)Pzr;
    const s16x8* Phh_v = (const s16x8*)Phh;

    float zreg[8][4];                // z kept in registers by waves 0..3
    s16x8 afrag[16];

    __syncthreads();

    for (int t = 0; t < T_LEN; ++t) {
        // ---------- phase A: per-row scalars ----------
        if (tid < ROWS) {
            int r = tid;
            size_t idx = (size_t)(r0 + r) * T_LEN + t;
            float xv = x[idx], xlv = xl[idx], iv = itv[idx], mv = msk[idx];
            float gx = __expf(-fmaxf(iv * wgx + bgxv, 0.f));
            float xm = xmean[r0 + r];
            xi_s[r] = mv * xv + (1.f - mv) * (gx * xlv + (1.f - gx) * xm);
            mt_s[r] = mv;
            it_s[r] = iv;
        }
        __syncthreads();

        // hd = gamma_h * h  (in place), bf16 copy into a_s
        #pragma unroll
        for (int s = 0; s < 2; ++s) {
            int c   = tid + s * 512;
            int kt  = c >> 6, cl = c & 63;
            int row = cl & 15;
            int kb  = kt * 32 + (cl >> 4) * 8;
            float itr = it_s[row];
            float hv[8]; ushort tmp[8];
            #pragma unroll
            for (int j = 0; j < 8; ++j) {
                int k = kb + j;
                float g  = __expf(-fmaxf(itr * Wgh[k] + bgh[k], 0.f));
                float hd = h_s[row][k] * g;
                hv[j] = hd;
                tmp[j] = f2bf(hd);
            }
            #pragma unroll
            for (int j = 0; j < 8; ++j) h_s[row][kb + j] = hv[j];
            *(s16x8*)&a_s[row * H_DIM + kb] = *(s16x8*)tmp;
        }
        __syncthreads();

        // ---------- phase B: GEMM1 (z,r) ----------
        #pragma unroll
        for (int kt = 0; kt < 16; ++kt) {
            int row = l & 15;
            int kb  = kt * 32 + (l >> 4) * 8;
            afrag[kt] = *(const s16x8*)&a_s[row * H_DIM + kb];
        }
        f32x4 acc[8];
        #pragma unroll
        for (int i = 0; i < 8; ++i) acc[i] = (f32x4){0.f, 0.f, 0.f, 0.f};
        #pragma unroll
        for (int i = 0; i < 8; ++i) {
            int g_nt = wv * 8 + i;
            s16x8 bfrag[16];
            #pragma unroll
            for (int kt = 0; kt < 16; ++kt)
                bfrag[kt] = Pzr_v[(size_t)(g_nt * 16 + kt) * 64 + l];
            #pragma unroll
            for (int kt = 0; kt < 16; ++kt)
                acc[i] = __builtin_amdgcn_mfma_f32_16x16x32_bf16(afrag[kt], bfrag[kt], acc[i], 0, 0, 0);
        }
        __syncthreads();   // all A-frag reads of a_s done before r-waves overwrite it

        {
            int colb = l & 15;
            int rowq = (l >> 4) * 4;
            float xiq[4], mtq[4];
            #pragma unroll
            for (int q = 0; q < 4; ++q) { xiq[q] = xi_s[rowq + q]; mtq[q] = mt_s[rowq + q]; }
            if (wv < 4) {                      // z gate -> registers
                #pragma unroll
                for (int i = 0; i < 8; ++i) {
                    int col = (wv * 8 + i) * 16 + colb;
                    float b0 = bz[col];
                    float w0 = Wz[(size_t)col * GATE_D];
                    float wL = Wz[(size_t)col * GATE_D + GATE_D - 1];
                    #pragma unroll
                    for (int q = 0; q < 4; ++q)
                        zreg[i][q] = sigmoid_f(acc[i][q] + b0 + xiq[q] * w0 + mtq[q] * wL);
                }
            } else {                           // r gate -> a_s *= r (in place)
                #pragma unroll
                for (int i = 0; i < 8; ++i) {
                    int col = ((wv - 4) * 8 + i) * 16 + colb;
                    float b0 = br[col];
                    float w0 = Wr[(size_t)col * GATE_D];
                    float wL = Wr[(size_t)col * GATE_D + GATE_D - 1];
                    #pragma unroll
                    for (int q = 0; q < 4; ++q) {
                        float rr = sigmoid_f(acc[i][q] + b0 + xiq[q] * w0 + mtq[q] * wL);
                        int row = rowq + q;
                        ushort hdu = a_s[row * H_DIM + col];
                        a_s[row * H_DIM + col] = f2bf(rr * bf2f(hdu));
                    }
                }
            }
        }
        __syncthreads();

        // ---------- phase C: GEMM2 (h~) ----------
        #pragma unroll
        for (int kt = 0; kt < 16; ++kt) {
            int row = l & 15;
            int kb  = kt * 32 + (l >> 4) * 8;
            afrag[kt] = *(const s16x8*)&a_s[row * H_DIM + kb];
        }
        f32x4 acc2[4];
        #pragma unroll
        for (int i = 0; i < 4; ++i) acc2[i] = (f32x4){0.f, 0.f, 0.f, 0.f};
        #pragma unroll
        for (int i = 0; i < 4; ++i) {
            int nt = wv * 4 + i;
            s16x8 bfrag[16];
            #pragma unroll
            for (int kt = 0; kt < 16; ++kt)
                bfrag[kt] = Phh_v[(size_t)(nt * 16 + kt) * 64 + l];
            #pragma unroll
            for (int kt = 0; kt < 16; ++kt)
                acc2[i] = __builtin_amdgcn_mfma_f32_16x16x32_bf16(afrag[kt], bfrag[kt], acc2[i], 0, 0, 0);
        }
        __syncthreads();   // rh reads done before h~ overwrites a_s

        {
            int colb = l & 15;
            int rowq = (l >> 4) * 4;
            float xiq[4], mtq[4];
            #pragma unroll
            for (int q = 0; q < 4; ++q) { xiq[q] = xi_s[rowq + q]; mtq[q] = mt_s[rowq + q]; }
            #pragma unroll
            for (int i = 0; i < 4; ++i) {
                int col = (wv * 4 + i) * 16 + colb;
                float b0 = bh[col];
                float w0 = Wh[(size_t)col * GATE_D];
                float wL = Wh[(size_t)col * GATE_D + GATE_D - 1];
                #pragma unroll
                for (int q = 0; q < 4; ++q) {
                    float ht = tanh_f(acc2[i][q] + b0 + xiq[q] * w0 + mtq[q] * wL);
                    a_s[(rowq + q) * H_DIM + col] = f2bf(ht);
                }
            }
        }
        __syncthreads();

        // ---------- phase D: state update (z-waves) ----------
        if (wv < 4) {
            #pragma unroll
            for (int i = 0; i < 8; ++i) {
                int col = (wv * 8 + i) * 16 + (l & 15);
                #pragma unroll
                for (int q = 0; q < 4; ++q) {
                    int row = (l >> 4) * 4 + q;
                    float hd = h_s[row][col];
                    float ht = bf2f(a_s[row * H_DIM + col]);
                    float z  = zreg[i][q];
                    h_s[row][col] = hd + z * (ht - hd);
                }
            }
        }
        __syncthreads();
    }

    // ---------- output head ----------
    #pragma unroll
    for (int rr = 0; rr < 2; ++rr) {
        int row = wv * 2 + rr;
        float s = 0.f;
        #pragma unroll
        for (int jj = 0; jj < H_DIM / 64; ++jj) {
            int j = l + jj * 64;
            s += h_s[row][j] * Wo[j];
        }
        for (int off = 32; off; off >>= 1) s += __shfl_down(s, off);
        if (l == 0) out[r0 + row] = sigmoid_f(s + bo[0]);
    }
}

extern "C" void kernel_launch(void* const* d_in, const int* in_sizes, int n_in,
                              void* d_out, int out_size, void* d_ws, size_t ws_size,
                              hipStream_t stream) {
    const float* x    = (const float*)d_in[0];
    const float* xl   = (const float*)d_in[1];
    const float* itv  = (const float*)d_in[2];
    const float* msk  = (const float*)d_in[3];
    const float* Wgx  = (const float*)d_in[4];
    const float* bgx  = (const float*)d_in[5];
    const float* Wgh  = (const float*)d_in[6];
    const float* bgh  = (const float*)d_in[7];
    const float* Wz   = (const float*)d_in[8];
    const float* bz   = (const float*)d_in[9];
    const float* Wr   = (const float*)d_in[10];
    const float* br   = (const float*)d_in[11];
    const float* Wh   = (const float*)d_in[12];
    const float* bh   = (const float*)d_in[13];
    const float* Wo   = (const float*)d_in[14];
    const float* bo   = (const float*)d_in[15];

    char* ws = (char*)d_ws;
    float*  xmean = (float*)ws;                          // 4096 f32 = 16KB
    ushort* Pzr   = (ushort*)(ws + (16 << 10));          // 1024 frags * 1KB = 1MB
    ushort* Phh   = (ushort*)(ws + (16 << 10) + (1 << 20)); // 512 frags = 0.5MB

    k_xmean<<<B_TOT, 64, 0, stream>>>(x, msk, xmean);
    k_pack<<<1536, 64, 0, stream>>>(Wz, Wr, Wh, Pzr, Phh);
    k_grud<<<NBLK, 512, 0, stream>>>(x, xl, itv, msk, Wgx, bgx, Wgh, bgh,
                                     Wz, bz, Wr, br, Wh, bh, Wo, bo,
                                     xmean, Pzr, Phh, (float*)d_out);
}

// Round 2
// 36364.783 us; speedup vs baseline: 1.4642x; 1.4642x over previous
//
#include <hip/hip_runtime.h>
#include <stdint.h>

#define T_LEN 512
#define H_DIM 512
#define B_TOT 4096
#define GATE_D 514
#define ROWS 32
#define NBLK (B_TOT / ROWS)   // 128
#define NTHR 1024
#define HS 520                // padded h_s stride in floats

typedef short s16x8 __attribute__((ext_vector_type(8)));
typedef float f32x4 __attribute__((ext_vector_type(4)));

__device__ __forceinline__ ushort f2bf(float f) {
    uint32_t u = __builtin_bit_cast(uint32_t, f);
    u += 0x7FFF + ((u >> 16) & 1);     // RNE
    return (ushort)(u >> 16);
}
__device__ __forceinline__ float bf2f(ushort h) {
    uint32_t u = ((uint32_t)h) << 16;
    return __builtin_bit_cast(float, u);
}
__device__ __forceinline__ float sigmoid_f(float x) {
    return 1.0f / (1.0f + __expf(-x));
}
__device__ __forceinline__ float tanh_f(float x) {
    float ax = fabsf(x);
    float e  = __expf(2.0f * ax);
    float t  = 1.0f - 2.0f / (e + 1.0f);
    return copysignf(t, x);
}

// ---------------- K0: masked mean over time ----------------
__global__ void k_xmean(const float* __restrict__ x, const float* __restrict__ m,
                        float* __restrict__ xmean) {
    int b = blockIdx.x;
    int l = threadIdx.x;
    const float* xr = x + (size_t)b * T_LEN;
    const float* mr = m + (size_t)b * T_LEN;
    float sx = 0.f, sm = 0.f;
    #pragma unroll
    for (int i = 0; i < T_LEN / 64; ++i) {
        float mv = mr[l + i * 64];
        sx += xr[l + i * 64] * mv;
        sm += mv;
    }
    for (int off = 32; off; off >>= 1) {
        sx += __shfl_down(sx, off);
        sm += __shfl_down(sm, off);
    }
    if (l == 0) xmean[b] = sx / sm;
}

// ---------------- K1: pack weights to bf16 MFMA B-fragments ----------------
// Fragment (g_nt, kt): elem[(frag*64 + lane)*8 + j] = W[n][1 + kt*32 + (lane>>4)*8 + j]
// with n = ntl*16 + (lane&15). Columns 0 and 513 (xi, mask) stay fp32 in epilogue.
__global__ void k_pack(const float* __restrict__ Wz, const float* __restrict__ Wr,
                       const float* __restrict__ Wh,
                       ushort* __restrict__ zr, ushort* __restrict__ hh) {
    int bid = blockIdx.x;
    int l = threadIdx.x;
    const float* src;
    ushort* dst;
    int ntl, kt;
    if (bid < 1024) {                 // Wz (g_nt 0..31) then Wr (32..63)
        int g_nt = bid >> 4; kt = bid & 15;
        src = (g_nt < 32) ? Wz : Wr;
        ntl = g_nt & 31;
        dst = zr + ((size_t)bid * 64 + l) * 8;
    } else {
        int id = bid - 1024;          // Wh, nt 0..31
        int nt = id >> 4; kt = id & 15;
        src = Wh; ntl = nt;
        dst = hh + ((size_t)id * 64 + l) * 8;
    }
    int wrow = ntl * 16 + (l & 15);
    int c0 = 1 + kt * 32 + (l >> 4) * 8;
    ushort tmp[8];
    #pragma unroll
    for (int j = 0; j < 8; ++j) tmp[j] = f2bf(src[(size_t)wrow * GATE_D + c0 + j]);
    *(s16x8*)dst = *(s16x8*)tmp;
}

// ---------------- main persistent kernel ----------------
// 128 blocks x 1024 threads (16 waves, 4/SIMD). Block owns 32 batch rows for all T.
// A-operands kept in FRAGMENT-MAJOR LDS layout -> conflict-free ds_read_b128.
// Wave w owns output cols [32w, 32w+32): z kept in regs, D fused into GEMM2 epilogue.
__global__ __launch_bounds__(NTHR, 4) void k_grud(
    const float* __restrict__ x,   const float* __restrict__ xl,
    const float* __restrict__ itv, const float* __restrict__ msk,
    const float* __restrict__ Wgx, const float* __restrict__ bgx,
    const float* __restrict__ Wgh, const float* __restrict__ bgh,
    const float* __restrict__ Wz,  const float* __restrict__ bz,
    const float* __restrict__ Wr,  const float* __restrict__ br,
    const float* __restrict__ Wh,  const float* __restrict__ bh,
    const float* __restrict__ Wo,  const float* __restrict__ bo,
    const float* __restrict__ xmean,
    const ushort* __restrict__ Pzr, const ushort* __restrict__ Phh,
    float* __restrict__ out)
{
    __shared__ float  h_s[ROWS * HS];          // 66560 B  fp32 state (hd after phase A)
    __shared__ ushort a_frag[32 * 512];        // 32768 B  32 MFMA A-fragments (frag-major)
    __shared__ float4 epi_s[3 * 512];          // 24576 B  {bias, W[:,0], W[:,513]} per gate/col
    __shared__ float2 ghb_s[H_DIM];            // 4096 B   {Wgh[k], bgh[k]}
    __shared__ float  xi_s[2][ROWS], mts_s[2][ROWS], its_s[2][ROWS];

    const int tid = threadIdx.x;
    const int wv  = tid >> 6;        // 0..15
    const int l   = tid & 63;
    const int r0  = blockIdx.x * ROWS;

    // ---- prologue: init LDS ----
    for (int i = tid; i < ROWS * HS; i += NTHR) h_s[i] = 0.0f;
    for (int i = tid; i < 3 * 512; i += NTHR) {
        int g = i >> 9, c = i & 511;
        const float* W  = (g == 0) ? Wz : (g == 1) ? Wr : Wh;
        const float* bb = (g == 0) ? bz : (g == 1) ? br : bh;
        epi_s[i] = make_float4(bb[c], W[(size_t)c * GATE_D],
                               W[(size_t)c * GATE_D + GATE_D - 1], 0.f);
    }
    if (tid < H_DIM) ghb_s[tid] = make_float2(Wgh[tid], bgh[tid]);
    if (tid < ROWS) {           // phase A for t=0 -> slot 0
        int rr = tid;
        size_t idx = (size_t)(r0 + rr) * T_LEN;
        float xv = x[idx], xlv = xl[idx], iv = itv[idx], mv = msk[idx];
        float gx = __expf(-fmaxf(iv * Wgx[0] + bgx[0], 0.f));
        xi_s[0][rr]  = mv * xv + (1.f - mv) * (gx * xlv + (1.f - gx) * xmean[r0 + rr]);
        mts_s[0][rr] = mv;
        its_s[0][rr] = iv;
    }
    __syncthreads();

    const s16x8* AF  = (const s16x8*)a_frag;
    const s16x8* pzb = (const s16x8*)Pzr + (size_t)(2 * wv) * 1024 + l;        // z tiles
    const s16x8* prb = (const s16x8*)Pzr + (size_t)(32 + 2 * wv) * 1024 + l;   // r tiles
    const s16x8* phb = (const s16x8*)Phh + (size_t)(2 * wv) * 1024 + l;        // h~ tiles

    const int colb = l & 15;
    const int qg   = l >> 4;

    for (int t = 0; t < T_LEN; ++t) {
        const int sl = t & 1;

        // ---------- hd phase: h *= gamma_h (in h_s, fp32); bf16 frags -> a_frag ----------
        {
            int f  = tid >> 5;           // fragment 0..31 (mt = f>>4, kt = f&15)
            int hh = tid & 31;
            int kt_f = f & 15, mt_f = f >> 4;
            #pragma unroll
            for (int li = 0; li < 2; ++li) {
                int ln  = 2 * hh + li;
                int row = mt_f * 16 + (ln & 15);
                int kb  = kt_f * 32 + (ln >> 4) * 8;
                float it = its_s[sl][row];
                float hv[8]; ushort tb[8];
                #pragma unroll
                for (int j = 0; j < 8; ++j) {
                    int k = kb + j;
                    float2 gb = ghb_s[k];
                    float g  = __expf(-fmaxf(it * gb.x + gb.y, 0.f));
                    float hd = h_s[row * HS + k] * g;
                    hv[j] = hd; tb[j] = f2bf(hd);
                }
                #pragma unroll
                for (int j = 0; j < 8; ++j) h_s[row * HS + kb + j] = hv[j];
                *(s16x8*)&a_frag[(f * 64 + ln) * 8] = *(s16x8*)tb;
            }
        }
        __syncthreads();   // bar1: a_frag(hd) + h_s(hd) ready

        // phase A for t+1 overlaps GEMM1 (double-buffered scalars)
        if (tid < ROWS && t + 1 < T_LEN) {
            int rr = tid;
            size_t idx = (size_t)(r0 + rr) * T_LEN + t + 1;
            float xv = x[idx], xlv = xl[idx], iv = itv[idx], mv = msk[idx];
            float gx = __expf(-fmaxf(iv * Wgx[0] + bgx[0], 0.f));
            int s2 = (t + 1) & 1;
            xi_s[s2][rr]  = mv * xv + (1.f - mv) * (gx * xlv + (1.f - gx) * xmean[r0 + rr]);
            mts_s[s2][rr] = mv;
            its_s[s2][rr] = iv;
        }

        // ---------- GEMM1: z and r for this wave's 32 cols ----------
        f32x4 accz[2][2], accr[2][2];
        #pragma unroll
        for (int mt = 0; mt < 2; ++mt)
            #pragma unroll
            for (int n = 0; n < 2; ++n) { accz[mt][n] = (f32x4){0,0,0,0}; accr[mt][n] = (f32x4){0,0,0,0}; }

        #pragma unroll
        for (int kq = 0; kq < 4; ++kq) {
            s16x8 af[2][4];
            #pragma unroll
            for (int mt = 0; mt < 2; ++mt)
                #pragma unroll
                for (int kk = 0; kk < 4; ++kk)
                    af[mt][kk] = AF[(mt * 16 + kq * 4 + kk) * 64 + l];
            #pragma unroll
            for (int n = 0; n < 2; ++n) {
                s16x8 bfz[4], bfr[4];
                #pragma unroll
                for (int kk = 0; kk < 4; ++kk) {
                    bfz[kk] = pzb[n * 1024 + (kq * 4 + kk) * 64];
                    bfr[kk] = prb[n * 1024 + (kq * 4 + kk) * 64];
                }
                #pragma unroll
                for (int kk = 0; kk < 4; ++kk)
                    #pragma unroll
                    for (int mt = 0; mt < 2; ++mt) {
                        accz[mt][n] = __builtin_amdgcn_mfma_f32_16x16x32_bf16(af[mt][kk], bfz[kk], accz[mt][n], 0, 0, 0);
                        accr[mt][n] = __builtin_amdgcn_mfma_f32_16x16x32_bf16(af[mt][kk], bfr[kk], accr[mt][n], 0, 0, 0);
                    }
            }
        }

        // ---------- z, r epilogue (registers only) ----------
        float zq[2][2][4], rq[2][2][4];
        {
            float xiq[2][4], mtq[2][4];
            #pragma unroll
            for (int mt = 0; mt < 2; ++mt)
                #pragma unroll
                for (int q = 0; q < 4; ++q) {
                    int row = mt * 16 + qg * 4 + q;
                    xiq[mt][q] = xi_s[sl][row];
                    mtq[mt][q] = mts_s[sl][row];
                }
            #pragma unroll
            for (int n = 0; n < 2; ++n) {
                int col = (2 * wv + n) * 16 + colb;
                float4 ez = epi_s[col];
                float4 er = epi_s[512 + col];
                #pragma unroll
                for (int mt = 0; mt < 2; ++mt)
                    #pragma unroll
                    for (int q = 0; q < 4; ++q) {
                        zq[mt][n][q] = sigmoid_f(accz[mt][n][q] + ez.x + xiq[mt][q] * ez.y + mtq[mt][q] * ez.z);
                        rq[mt][n][q] = sigmoid_f(accr[mt][n][q] + er.x + xiq[mt][q] * er.y + mtq[mt][q] * er.z);
                    }
            }
        }
        __syncthreads();   // bar2: all a_frag(hd) reads done

        // ---------- scatter r*hd into a_frag (transpose into frag kt = wv) ----------
        #pragma unroll
        for (int n = 0; n < 2; ++n) {
            int col = (2 * wv + n) * 16 + colb;     // col == k index of GEMM2, kt = wv
            int lgrp = ((col >> 3) & 3) << 4;
            int jj   = col & 7;
            #pragma unroll
            for (int mt = 0; mt < 2; ++mt)
                #pragma unroll
                for (int q = 0; q < 4; ++q) {
                    int row = mt * 16 + qg * 4 + q;
                    float hd = h_s[row * HS + col];
                    a_frag[((mt * 16 + wv) * 64 + (row & 15) + lgrp) * 8 + jj] =
                        f2bf(rq[mt][n][q] * hd);
                }
        }
        __syncthreads();   // bar3: a_frag(r*hd) ready

        // ---------- GEMM2: h~ ----------
        f32x4 acc2[2][2];
        #pragma unroll
        for (int mt = 0; mt < 2; ++mt)
            #pragma unroll
            for (int n = 0; n < 2; ++n) acc2[mt][n] = (f32x4){0,0,0,0};
        #pragma unroll
        for (int kq = 0; kq < 4; ++kq) {
            s16x8 af[2][4];
            #pragma unroll
            for (int mt = 0; mt < 2; ++mt)
                #pragma unroll
                for (int kk = 0; kk < 4; ++kk)
                    af[mt][kk] = AF[(mt * 16 + kq * 4 + kk) * 64 + l];
            #pragma unroll
            for (int n = 0; n < 2; ++n) {
                s16x8 bf[4];
                #pragma unroll
                for (int kk = 0; kk < 4; ++kk)
                    bf[kk] = phb[n * 1024 + (kq * 4 + kk) * 64];
                #pragma unroll
                for (int kk = 0; kk < 4; ++kk)
                    #pragma unroll
                    for (int mt = 0; mt < 2; ++mt)
                        acc2[mt][n] = __builtin_amdgcn_mfma_f32_16x16x32_bf16(af[mt][kk], bf[kk], acc2[mt][n], 0, 0, 0);
            }
        }

        // ---------- h~ epilogue + fused state update (own 32 cols) ----------
        #pragma unroll
        for (int n = 0; n < 2; ++n) {
            int col = (2 * wv + n) * 16 + colb;
            float4 eh = epi_s[1024 + col];
            #pragma unroll
            for (int mt = 0; mt < 2; ++mt)
                #pragma unroll
                for (int q = 0; q < 4; ++q) {
                    int row = mt * 16 + qg * 4 + q;
                    float xiv = xi_s[sl][row], mtv = mts_s[sl][row];
                    float ht = tanh_f(acc2[mt][n][q] + eh.x + xiv * eh.y + mtv * eh.z);
                    float hd = h_s[row * HS + col];
                    h_s[row * HS + col] = hd + zq[mt][n][q] * (ht - hd);
                }
        }
        __syncthreads();   // bar4: h_s(t) complete
    }

    // ---------- output head ----------
    #pragma unroll
    for (int rr = 0; rr < 2; ++rr) {
        int row = wv * 2 + rr;
        float s = 0.f;
        #pragma unroll
        for (int jj = 0; jj < H_DIM / 64; ++jj) {
            int j = l + jj * 64;
            s += h_s[row * HS + j] * Wo[j];
        }
        for (int off = 32; off; off >>= 1) s += __shfl_down(s, off);
        if (l == 0) out[r0 + row] = sigmoid_f(s + bo[0]);
    }
}

extern "C" void kernel_launch(void* const* d_in, const int* in_sizes, int n_in,
                              void* d_out, int out_size, void* d_ws, size_t ws_size,
                              hipStream_t stream) {
    const float* x    = (const float*)d_in[0];
    const float* xl   = (const float*)d_in[1];
    const float* itv  = (const float*)d_in[2];
    const float* msk  = (const float*)d_in[3];
    const float* Wgx  = (const float*)d_in[4];
    const float* bgx  = (const float*)d_in[5];
    const float* Wgh  = (const float*)d_in[6];
    const float* bgh  = (const float*)d_in[7];
    const float* Wz   = (const float*)d_in[8];
    const float* bz   = (const float*)d_in[9];
    const float* Wr   = (const float*)d_in[10];
    const float* br   = (const float*)d_in[11];
    const float* Wh   = (const float*)d_in[12];
    const float* bh   = (const float*)d_in[13];
    const float* Wo   = (const float*)d_in[14];
    const float* bo   = (const float*)d_in[15];

    char* ws = (char*)d_ws;
    float*  xmean = (float*)ws;                              // 16KB
    ushort* Pzr   = (ushort*)(ws + (16 << 10));              // 1MB
    ushort* Phh   = (ushort*)(ws + (16 << 10) + (1 << 20));  // 0.5MB

    k_xmean<<<B_TOT, 64, 0, stream>>>(x, msk, xmean);
    k_pack<<<1536, 64, 0, stream>>>(Wz, Wr, Wh, Pzr, Phh);
    k_grud<<<NBLK, NTHR, 0, stream>>>(x, xl, itv, msk, Wgx, bgx, Wgh, bgh,
                                      Wz, bz, Wr, br, Wh, bh, Wo, bo,
                                      xmean, Pzr, Phh, (float*)d_out);
}

// Round 3
// 31739.380 us; speedup vs baseline: 1.6776x; 1.1457x over previous
//
#include <hip/hip_runtime.h>
#include <stdint.h>

#define T_LEN 512
#define H_DIM 512
#define B_TOT 4096
#define GATE_D 514
#define CLUSTERS 16
#define RANKS 16        // blocks per cluster
#define CROWS 256       // batch rows per cluster
#define OWNC 32         // h-columns owned per block
#define NTHR 512        // 8 waves
#define HLS 33          // h_lds row stride (f32, padded)
#define RLS 34          // rhd_s row stride (ushort, padded)

typedef short s16x8 __attribute__((ext_vector_type(8)));
typedef float f32x4 __attribute__((ext_vector_type(4)));

__device__ __forceinline__ ushort f2bf(float f) {
    uint32_t u = __builtin_bit_cast(uint32_t, f);
    u += 0x7FFF + ((u >> 16) & 1);     // RNE
    return (ushort)(u >> 16);
}
__device__ __forceinline__ float sigmoid_f(float x) {
    return 1.0f / (1.0f + __expf(-x));
}
__device__ __forceinline__ float tanh_f(float x) {
    float ax = fabsf(x);
    float e  = __expf(2.0f * ax);
    float t  = 1.0f - 2.0f / (e + 1.0f);
    return copysignf(t, x);
}

// ---------------- K0: masked mean over time ----------------
__global__ void k_xmean(const float* __restrict__ x, const float* __restrict__ m,
                        float* __restrict__ xmean) {
    int b = blockIdx.x;
    int l = threadIdx.x;
    const float* xr = x + (size_t)b * T_LEN;
    const float* mr = m + (size_t)b * T_LEN;
    float sx = 0.f, sm = 0.f;
    #pragma unroll
    for (int i = 0; i < T_LEN / 64; ++i) {
        float mv = mr[l + i * 64];
        sx += xr[l + i * 64] * mv;
        sm += mv;
    }
    for (int off = 32; off; off >>= 1) {
        sx += __shfl_down(sx, off);
        sm += __shfl_down(sm, off);
    }
    if (l == 0) xmean[b] = sx / sm;
}

// ---------------- K_init: zero cluster barrier counters ----------------
__global__ void k_init(unsigned int* barc) {
    if (threadIdx.x < CLUSTERS) barc[threadIdx.x] = 0u;
}

// ---------------- cluster barrier (device-scope, monotone epoch) ----------------
__device__ __forceinline__ void cluster_bar(unsigned int* cnt, unsigned int target) {
    __syncthreads();                      // all threads' stores issued (vmcnt drained)
    if (threadIdx.x == 0) {
        __threadfence();                  // release: make block's global writes visible
        __hip_atomic_fetch_add(cnt, 1u, __ATOMIC_ACQ_REL, __HIP_MEMORY_SCOPE_AGENT);
        while (__hip_atomic_load(cnt, __ATOMIC_ACQUIRE, __HIP_MEMORY_SCOPE_AGENT) < target)
            __builtin_amdgcn_s_sleep(1);
        __threadfence();                  // acquire: invalidate caches before reads
    }
    __syncthreads();
}

// ---------------- main persistent kernel ----------------
// 256 blocks x 512 threads. Cluster = 16 blocks sharing 256 batch rows (same XCD by
// b%8 round-robin heuristic). Block rank j: weights for its 32 output cols of all 3
// gates in LDS (96 KB, resident), fp32 state h[256 x 32] in LDS. Per step: exchange
// bf16 hd / r*hd fragments through a cluster buffer (L2-hot), 2 cluster barriers.
__global__ __launch_bounds__(NTHR, 2) void k_grud(
    const float* __restrict__ x,   const float* __restrict__ xl,
    const float* __restrict__ itv, const float* __restrict__ msk,
    const float* __restrict__ Wgx, const float* __restrict__ bgx,
    const float* __restrict__ Wgh, const float* __restrict__ bgh,
    const float* __restrict__ Wz,  const float* __restrict__ bz,
    const float* __restrict__ Wr,  const float* __restrict__ br,
    const float* __restrict__ Wh,  const float* __restrict__ bh,
    const float* __restrict__ Wo,  const float* __restrict__ bo,
    const float* __restrict__ xmean,
    ushort* __restrict__ hdx, ushort* __restrict__ rhx,
    float* __restrict__ osum, unsigned int* __restrict__ barc,
    float* __restrict__ out)
{
    __shared__ ushort wfrag[96 * 512];        // 98304 B  weight B-fragments (z:0-31, r:32-63, h:64-95)
    __shared__ float  h_lds[CROWS * HLS];     // 33792 B  fp32 state / hd (own 32 cols)
    __shared__ ushort rhd_s[CROWS * RLS];     // 17408 B  r*hd staging (bf16)
    __shared__ float  xi_s[CROWS], mts_s[CROWS], its_s[CROWS];  // 3072 B
    __shared__ float4 epi_s[96];              // 1536 B   {bias, W[:,0], W[:,513]} per gate/own col
    __shared__ float2 ghb_s[OWNC];            // 256 B    {Wgh, bgh} own cols

    const int tid = threadIdx.x;
    const int b   = blockIdx.x;
    const int cluster = (b & 7) * 2 + ((b >> 3) >> 4);   // same-XCD grouping
    const int rank    = (b >> 3) & 15;
    const int wv = tid >> 6, l = tid & 63;
    const int colb = l & 15, qg = l >> 4;
    const int r0 = cluster * CROWS;

    unsigned int* cnt = barc + cluster;
    ushort* hdc = hdx + (size_t)cluster * CROWS * H_DIM;
    ushort* rhc = rhx + (size_t)cluster * CROWS * H_DIM;
    const s16x8* WF = (const s16x8*)wfrag;
    const s16x8* HD = (const s16x8*)hdc;
    const s16x8* RH = (const s16x8*)rhc;

    // ---- one-time init: state, weight fragments, epilogue tables ----
    for (int i = tid; i < CROWS * HLS; i += NTHR) h_lds[i] = 0.f;
    for (int s = tid; s < 96 * 64; s += NTHR) {
        int fi = s >> 6, ln = s & 63;
        int g = fi >> 5, nt = (fi >> 4) & 1, kt = fi & 15;
        const float* W = (g == 0) ? Wz : (g == 1) ? Wr : Wh;
        int colg = rank * OWNC + nt * 16 + (ln & 15);
        int c0 = 1 + kt * 32 + (ln >> 4) * 8;
        ushort tb[8];
        #pragma unroll
        for (int j = 0; j < 8; ++j) tb[j] = f2bf(W[(size_t)colg * GATE_D + c0 + j]);
        *(s16x8*)&wfrag[s * 8] = *(s16x8*)tb;
    }
    for (int i = tid; i < 96; i += NTHR) {
        int g = i >> 5, c = i & 31;
        const float* W  = (g == 0) ? Wz : (g == 1) ? Wr : Wh;
        const float* bb = (g == 0) ? bz : (g == 1) ? br : bh;
        int colg = rank * OWNC + c;
        epi_s[i] = make_float4(bb[colg], W[(size_t)colg * GATE_D],
                               W[(size_t)colg * GATE_D + GATE_D - 1], 0.f);
    }
    if (tid < OWNC) ghb_s[tid] = make_float2(Wgh[rank * OWNC + tid], bgh[rank * OWNC + tid]);
    const float wgx = Wgx[0], bgx0 = bgx[0];
    __syncthreads();

    float zq[2][2][4];

    for (int t = 0; t < T_LEN; ++t) {
        // ---- per-row scalars ----
        if (tid < CROWS) {
            size_t idx = (size_t)(r0 + tid) * T_LEN + t;
            float xv = x[idx], xlv = xl[idx], iv = itv[idx], mv = msk[idx];
            float gx = __expf(-fmaxf(iv * wgx + bgx0, 0.f));
            xi_s[tid]  = mv * xv + (1.f - mv) * (gx * xlv + (1.f - gx) * xmean[r0 + tid]);
            mts_s[tid] = mv;
            its_s[tid] = iv;
        }
        __syncthreads();

        // ---- phase 1: hd = gamma_h * h (fp32 in place) + bf16 frag -> hdx (kt = rank) ----
        #pragma unroll
        for (int i = 0; i < 2; ++i) {
            int s = tid + i * NTHR;            // 0..1023: (mt 0..15, ln 0..63)
            int mt = s >> 6, ln = s & 63;
            int row = mt * 16 + (ln & 15);
            int c0 = (ln >> 4) * 8;
            float it = its_s[row];
            float hv[8]; ushort tb[8];
            #pragma unroll
            for (int j = 0; j < 8; ++j) {
                float2 gb = ghb_s[c0 + j];
                float g  = __expf(-fmaxf(it * gb.x + gb.y, 0.f));
                float hd = h_lds[row * HLS + c0 + j] * g;
                hv[j] = hd; tb[j] = f2bf(hd);
            }
            #pragma unroll
            for (int j = 0; j < 8; ++j) h_lds[row * HLS + c0 + j] = hv[j];
            *(s16x8*)&hdc[((mt * 16 + rank) * 64 + ln) * 8] = *(s16x8*)tb;
        }
        cluster_bar(cnt, (unsigned int)(RANKS * (2 * t + 1)));

        // ---- GEMM1: z,r = hd (256x512) x W (512x64), wave rows [32wv, 32wv+32) ----
        f32x4 accz[2][2], accr[2][2];
        #pragma unroll
        for (int mt = 0; mt < 2; ++mt)
            #pragma unroll
            for (int nt = 0; nt < 2; ++nt) { accz[mt][nt] = (f32x4){0,0,0,0}; accr[mt][nt] = (f32x4){0,0,0,0}; }
        #pragma unroll
        for (int kt = 0; kt < 16; ++kt) {
            s16x8 a0 = HD[((2 * wv    ) * 16 + kt) * 64 + l];
            s16x8 a1 = HD[((2 * wv + 1) * 16 + kt) * 64 + l];
            #pragma unroll
            for (int nt = 0; nt < 2; ++nt) {
                s16x8 bz_ = WF[(     nt * 16 + kt) * 64 + l];
                s16x8 br_ = WF[(32 + nt * 16 + kt) * 64 + l];
                accz[0][nt] = __builtin_amdgcn_mfma_f32_16x16x32_bf16(a0, bz_, accz[0][nt], 0, 0, 0);
                accz[1][nt] = __builtin_amdgcn_mfma_f32_16x16x32_bf16(a1, bz_, accz[1][nt], 0, 0, 0);
                accr[0][nt] = __builtin_amdgcn_mfma_f32_16x16x32_bf16(a0, br_, accr[0][nt], 0, 0, 0);
                accr[1][nt] = __builtin_amdgcn_mfma_f32_16x16x32_bf16(a1, br_, accr[1][nt], 0, 0, 0);
            }
        }
        // ---- z,r epilogue: z -> regs, r*hd -> rhd_s ----
        #pragma unroll
        for (int mt = 0; mt < 2; ++mt) {
            #pragma unroll
            for (int nt = 0; nt < 2; ++nt) {
                int c = nt * 16 + colb;
                float4 ez = epi_s[c];
                float4 er = epi_s[32 + c];
                #pragma unroll
                for (int q = 0; q < 4; ++q) {
                    int row = wv * 32 + mt * 16 + qg * 4 + q;
                    float xiv = xi_s[row], mtv = mts_s[row];
                    zq[mt][nt][q] = sigmoid_f(accz[mt][nt][q] + ez.x + xiv * ez.y + mtv * ez.z);
                    float rr = sigmoid_f(accr[mt][nt][q] + er.x + xiv * er.y + mtv * er.z);
                    float hd = h_lds[row * HLS + c];
                    rhd_s[row * RLS + c] = f2bf(rr * hd);
                }
            }
        }
        __syncthreads();
        // ---- frag-copy rhd_s -> rhx (kt = rank) ----
        #pragma unroll
        for (int i = 0; i < 2; ++i) {
            int s = tid + i * NTHR;
            int mt = s >> 6, ln = s & 63;
            int row = mt * 16 + (ln & 15);
            int c0 = (ln >> 4) * 8;
            ushort tb[8];
            #pragma unroll
            for (int j = 0; j < 8; ++j) tb[j] = rhd_s[row * RLS + c0 + j];
            *(s16x8*)&rhc[((mt * 16 + rank) * 64 + ln) * 8] = *(s16x8*)tb;
        }
        cluster_bar(cnt, (unsigned int)(RANKS * (2 * t + 2)));

        // ---- GEMM2: h~ = (r*hd) x Wh (512x32) ----
        f32x4 acc2[2][2];
        #pragma unroll
        for (int mt = 0; mt < 2; ++mt)
            #pragma unroll
            for (int nt = 0; nt < 2; ++nt) acc2[mt][nt] = (f32x4){0,0,0,0};
        #pragma unroll
        for (int kt = 0; kt < 16; ++kt) {
            s16x8 a0 = RH[((2 * wv    ) * 16 + kt) * 64 + l];
            s16x8 a1 = RH[((2 * wv + 1) * 16 + kt) * 64 + l];
            #pragma unroll
            for (int nt = 0; nt < 2; ++nt) {
                s16x8 bh_ = WF[(64 + nt * 16 + kt) * 64 + l];
                acc2[0][nt] = __builtin_amdgcn_mfma_f32_16x16x32_bf16(a0, bh_, acc2[0][nt], 0, 0, 0);
                acc2[1][nt] = __builtin_amdgcn_mfma_f32_16x16x32_bf16(a1, bh_, acc2[1][nt], 0, 0, 0);
            }
        }
        // ---- h~ epilogue + fused state update (all local) ----
        #pragma unroll
        for (int mt = 0; mt < 2; ++mt) {
            #pragma unroll
            for (int nt = 0; nt < 2; ++nt) {
                int c = nt * 16 + colb;
                float4 eh = epi_s[64 + c];
                #pragma unroll
                for (int q = 0; q < 4; ++q) {
                    int row = wv * 32 + mt * 16 + qg * 4 + q;
                    float ht = tanh_f(acc2[mt][nt][q] + eh.x + xi_s[row] * eh.y + mts_s[row] * eh.z);
                    float hd = h_lds[row * HLS + c];
                    h_lds[row * HLS + c] = hd + zq[mt][nt][q] * (ht - hd);
                }
            }
        }
        __syncthreads();   // protect xi_s/h_lds before next step's overwrite
    }

    // ---- output head: partial dot over own 32 cols, deterministic cross-rank sum ----
    if (tid < CROWS) {
        float s = 0.f;
        #pragma unroll
        for (int c = 0; c < OWNC; ++c) s += h_lds[tid * HLS + c] * Wo[rank * OWNC + c];
        osum[(size_t)(r0 + tid) * RANKS + rank] = s;
    }
    cluster_bar(cnt, (unsigned int)(RANKS * (2 * T_LEN + 1)));
    if (rank == 0 && tid < CROWS) {
        float s = 0.f;
        #pragma unroll
        for (int rk = 0; rk < RANKS; ++rk) s += osum[(size_t)(r0 + tid) * RANKS + rk];
        out[r0 + tid] = sigmoid_f(s + bo[0]);
    }
}

extern "C" void kernel_launch(void* const* d_in, const int* in_sizes, int n_in,
                              void* d_out, int out_size, void* d_ws, size_t ws_size,
                              hipStream_t stream) {
    const float* x    = (const float*)d_in[0];
    const float* xl   = (const float*)d_in[1];
    const float* itv  = (const float*)d_in[2];
    const float* msk  = (const float*)d_in[3];
    const float* Wgx  = (const float*)d_in[4];
    const float* bgx  = (const float*)d_in[5];
    const float* Wgh  = (const float*)d_in[6];
    const float* bgh  = (const float*)d_in[7];
    const float* Wz   = (const float*)d_in[8];
    const float* bz   = (const float*)d_in[9];
    const float* Wr   = (const float*)d_in[10];
    const float* br   = (const float*)d_in[11];
    const float* Wh   = (const float*)d_in[12];
    const float* bh   = (const float*)d_in[13];
    const float* Wo   = (const float*)d_in[14];
    const float* bo   = (const float*)d_in[15];

    char* ws = (char*)d_ws;
    float*        xmean = (float*)ws;                          // 16384 B
    unsigned int* barc  = (unsigned int*)(ws + 16384);         // 256 B (16 used)
    float*        osum  = (float*)(ws + 16640);                // 4096*16*4 = 262144 B
    ushort*       hdx   = (ushort*)(ws + 16640 + 262144);      // 4 MB
    ushort*       rhx   = (ushort*)(ws + 16640 + 262144 + 4194304); // 4 MB

    k_init<<<1, 64, 0, stream>>>(barc);
    k_xmean<<<B_TOT, 64, 0, stream>>>(x, msk, xmean);
    k_grud<<<CLUSTERS * RANKS, NTHR, 0, stream>>>(
        x, xl, itv, msk, Wgx, bgx, Wgh, bgh,
        Wz, bz, Wr, br, Wh, bh, Wo, bo,
        xmean, hdx, rhx, osum, barc, (float*)d_out);
}

// Round 4
// 14824.883 us; speedup vs baseline: 3.5916x; 2.1410x over previous
//
#include <hip/hip_runtime.h>
#include <stdint.h>

#define T_LEN 512
#define H_DIM 512
#define B_TOT 4096
#define GATE_D 514
#define CLUSTERS 16
#define RANKS 16        // blocks per cluster
#define CROWS 256       // batch rows per cluster
#define OWNC 32         // h-columns owned per block
#define NTHR 512        // 8 waves
#define HLS 33          // h_lds row stride (f32, padded)
#define RLS 34          // rhd_s row stride (ushort, padded)
#define BARPAD 64       // uints between cluster counters (256B)

typedef short s16x8 __attribute__((ext_vector_type(8)));
typedef float f32x4 __attribute__((ext_vector_type(4)));

__device__ __forceinline__ ushort f2bf(float f) {
    uint32_t u = __builtin_bit_cast(uint32_t, f);
    u += 0x7FFF + ((u >> 16) & 1);     // RNE
    return (ushort)(u >> 16);
}
__device__ __forceinline__ float sigmoid_f(float x) {
    return 1.0f / (1.0f + __expf(-x));
}
__device__ __forceinline__ float tanh_f(float x) {
    float ax = fabsf(x);
    float e  = __expf(2.0f * ax);
    float t  = 1.0f - 2.0f / (e + 1.0f);
    return copysignf(t, x);
}

// ---------------- K0: masked mean over time ----------------
__global__ void k_xmean(const float* __restrict__ x, const float* __restrict__ m,
                        float* __restrict__ xmean) {
    int b = blockIdx.x;
    int l = threadIdx.x;
    const float* xr = x + (size_t)b * T_LEN;
    const float* mr = m + (size_t)b * T_LEN;
    float sx = 0.f, sm = 0.f;
    #pragma unroll
    for (int i = 0; i < T_LEN / 64; ++i) {
        float mv = mr[l + i * 64];
        sx += xr[l + i * 64] * mv;
        sm += mv;
    }
    for (int off = 32; off; off >>= 1) {
        sx += __shfl_down(sx, off);
        sm += __shfl_down(sm, off);
    }
    if (l == 0) xmean[b] = sx / sm;
}

// ---------------- K_init: zero padded cluster barrier counters ----------------
__global__ void k_init(unsigned int* barc) {
    int i = threadIdx.x + blockIdx.x * blockDim.x;
    if (i < CLUSTERS * BARPAD) barc[i] = 0u;
}

// ---------------- cluster barrier ----------------
// Lean protocol: ONE release fence (waitcnt+wbl2) + relaxed add; RELAXED polling
// (no cache ops per iteration!); ONE acquire fence (buffer_inv) on exit.
__device__ __forceinline__ void cluster_bar(unsigned int* cnt, unsigned int target) {
    __syncthreads();
    if (threadIdx.x == 0) {
        __builtin_amdgcn_fence(__ATOMIC_RELEASE, "agent");
        __hip_atomic_fetch_add(cnt, 1u, __ATOMIC_RELAXED, __HIP_MEMORY_SCOPE_AGENT);
        while (__hip_atomic_load(cnt, __ATOMIC_RELAXED, __HIP_MEMORY_SCOPE_AGENT) < target)
            __builtin_amdgcn_s_sleep(2);
        __builtin_amdgcn_fence(__ATOMIC_ACQUIRE, "agent");
    }
    __syncthreads();
}

// ---------------- main persistent kernel ----------------
// 256 blocks x 512 threads. Cluster = 16 blocks sharing 256 batch rows (same XCD by
// b%8 round-robin heuristic; correctness does NOT depend on it — agent-scope fences).
// Block rank j: weights for its 32 output cols of all 3 gates in LDS (96 KB, resident),
// fp32 state h[256 x 32] in LDS. Per step: exchange bf16 hd / r*hd fragments through
// an L2-hot cluster buffer, 2 cluster barriers.
__global__ __launch_bounds__(NTHR, 2) void k_grud(
    const float* __restrict__ x,   const float* __restrict__ xl,
    const float* __restrict__ itv, const float* __restrict__ msk,
    const float* __restrict__ Wgx, const float* __restrict__ bgx,
    const float* __restrict__ Wgh, const float* __restrict__ bgh,
    const float* __restrict__ Wz,  const float* __restrict__ bz,
    const float* __restrict__ Wr,  const float* __restrict__ br,
    const float* __restrict__ Wh,  const float* __restrict__ bh,
    const float* __restrict__ Wo,  const float* __restrict__ bo,
    const float* __restrict__ xmean,
    ushort* __restrict__ hdx, ushort* __restrict__ rhx,
    float* __restrict__ osum, unsigned int* __restrict__ barc,
    float* __restrict__ out)
{
    __shared__ ushort wfrag[96 * 512];        // 98304 B  weight B-fragments (z:0-31, r:32-63, h:64-95)
    __shared__ float  h_lds[CROWS * HLS];     // 33792 B  fp32 state / hd (own 32 cols)
    __shared__ ushort rhd_s[CROWS * RLS];     // 17408 B  r*hd staging (bf16)
    __shared__ float  xi_s[CROWS], mts_s[CROWS], its_s[CROWS];  // 3072 B
    __shared__ float4 epi_s[96];              // 1536 B   {bias, W[:,0], W[:,513]} per gate/own col
    __shared__ float2 ghb_s[OWNC];            // 256 B    {Wgh, bgh} own cols

    const int tid = threadIdx.x;
    const int b   = blockIdx.x;
    const int cluster = (b & 7) * 2 + ((b >> 3) >> 4);   // same-XCD grouping heuristic
    const int rank    = (b >> 3) & 15;
    const int wv = tid >> 6, l = tid & 63;
    const int colb = l & 15, qg = l >> 4;
    const int r0 = cluster * CROWS;

    unsigned int* cnt = barc + cluster * BARPAD;
    ushort* hdc = hdx + (size_t)cluster * CROWS * H_DIM;
    ushort* rhc = rhx + (size_t)cluster * CROWS * H_DIM;
    const s16x8* WF = (const s16x8*)wfrag;
    const s16x8* HD = (const s16x8*)hdc;
    const s16x8* RH = (const s16x8*)rhc;

    // ---- one-time init: state, weight fragments, epilogue tables ----
    for (int i = tid; i < CROWS * HLS; i += NTHR) h_lds[i] = 0.f;
    for (int s = tid; s < 96 * 64; s += NTHR) {
        int fi = s >> 6, ln = s & 63;
        int g = fi >> 5, nt = (fi >> 4) & 1, kt = fi & 15;
        const float* W = (g == 0) ? Wz : (g == 1) ? Wr : Wh;
        int colg = rank * OWNC + nt * 16 + (ln & 15);
        int c0 = 1 + kt * 32 + (ln >> 4) * 8;
        ushort tb[8];
        #pragma unroll
        for (int j = 0; j < 8; ++j) tb[j] = f2bf(W[(size_t)colg * GATE_D + c0 + j]);
        *(s16x8*)&wfrag[s * 8] = *(s16x8*)tb;
    }
    for (int i = tid; i < 96; i += NTHR) {
        int g = i >> 5, c = i & 31;
        const float* W  = (g == 0) ? Wz : (g == 1) ? Wr : Wh;
        const float* bb = (g == 0) ? bz : (g == 1) ? br : bh;
        int colg = rank * OWNC + c;
        epi_s[i] = make_float4(bb[colg], W[(size_t)colg * GATE_D],
                               W[(size_t)colg * GATE_D + GATE_D - 1], 0.f);
    }
    if (tid < OWNC) ghb_s[tid] = make_float2(Wgh[rank * OWNC + tid], bgh[rank * OWNC + tid]);
    const float wgx = Wgx[0], bgx0 = bgx[0];
    __syncthreads();

    float zq[2][2][4];

    for (int t = 0; t < T_LEN; ++t) {
        // ---- per-row scalars ----
        if (tid < CROWS) {
            size_t idx = (size_t)(r0 + tid) * T_LEN + t;
            float xv = x[idx], xlv = xl[idx], iv = itv[idx], mv = msk[idx];
            float gx = __expf(-fmaxf(iv * wgx + bgx0, 0.f));
            xi_s[tid]  = mv * xv + (1.f - mv) * (gx * xlv + (1.f - gx) * xmean[r0 + tid]);
            mts_s[tid] = mv;
            its_s[tid] = iv;
        }
        __syncthreads();

        // ---- phase 1: hd = gamma_h * h (fp32 in place) + bf16 frag -> hdx (kt = rank) ----
        #pragma unroll
        for (int i = 0; i < 2; ++i) {
            int s = tid + i * NTHR;            // 0..1023: (mt 0..15, ln 0..63)
            int mt = s >> 6, ln = s & 63;
            int row = mt * 16 + (ln & 15);
            int c0 = (ln >> 4) * 8;
            float it = its_s[row];
            float hv[8]; ushort tb[8];
            #pragma unroll
            for (int j = 0; j < 8; ++j) {
                float2 gb = ghb_s[c0 + j];
                float g  = __expf(-fmaxf(it * gb.x + gb.y, 0.f));
                float hd = h_lds[row * HLS + c0 + j] * g;
                hv[j] = hd; tb[j] = f2bf(hd);
            }
            #pragma unroll
            for (int j = 0; j < 8; ++j) h_lds[row * HLS + c0 + j] = hv[j];
            *(s16x8*)&hdc[((mt * 16 + rank) * 64 + ln) * 8] = *(s16x8*)tb;
        }
        cluster_bar(cnt, (unsigned int)(RANKS * (2 * t + 1)));

        // ---- GEMM1: z,r = hd (256x512) x W (512x64), wave rows [32wv, 32wv+32) ----
        f32x4 accz[2][2], accr[2][2];
        #pragma unroll
        for (int mt = 0; mt < 2; ++mt)
            #pragma unroll
            for (int nt = 0; nt < 2; ++nt) { accz[mt][nt] = (f32x4){0,0,0,0}; accr[mt][nt] = (f32x4){0,0,0,0}; }
        #pragma unroll
        for (int kt = 0; kt < 16; ++kt) {
            s16x8 a0 = HD[((2 * wv    ) * 16 + kt) * 64 + l];
            s16x8 a1 = HD[((2 * wv + 1) * 16 + kt) * 64 + l];
            #pragma unroll
            for (int nt = 0; nt < 2; ++nt) {
                s16x8 bz_ = WF[(     nt * 16 + kt) * 64 + l];
                s16x8 br_ = WF[(32 + nt * 16 + kt) * 64 + l];
                accz[0][nt] = __builtin_amdgcn_mfma_f32_16x16x32_bf16(a0, bz_, accz[0][nt], 0, 0, 0);
                accz[1][nt] = __builtin_amdgcn_mfma_f32_16x16x32_bf16(a1, bz_, accz[1][nt], 0, 0, 0);
                accr[0][nt] = __builtin_amdgcn_mfma_f32_16x16x32_bf16(a0, br_, accr[0][nt], 0, 0, 0);
                accr[1][nt] = __builtin_amdgcn_mfma_f32_16x16x32_bf16(a1, br_, accr[1][nt], 0, 0, 0);
            }
        }
        // ---- z,r epilogue: z -> regs, r*hd -> rhd_s ----
        #pragma unroll
        for (int mt = 0; mt < 2; ++mt) {
            #pragma unroll
            for (int nt = 0; nt < 2; ++nt) {
                int c = nt * 16 + colb;
                float4 ez = epi_s[c];
                float4 er = epi_s[32 + c];
                #pragma unroll
                for (int q = 0; q < 4; ++q) {
                    int row = wv * 32 + mt * 16 + qg * 4 + q;
                    float xiv = xi_s[row], mtv = mts_s[row];
                    zq[mt][nt][q] = sigmoid_f(accz[mt][nt][q] + ez.x + xiv * ez.y + mtv * ez.z);
                    float rr = sigmoid_f(accr[mt][nt][q] + er.x + xiv * er.y + mtv * er.z);
                    float hd = h_lds[row * HLS + c];
                    rhd_s[row * RLS + c] = f2bf(rr * hd);
                }
            }
        }
        __syncthreads();
        // ---- frag-copy rhd_s -> rhx (kt = rank) ----
        #pragma unroll
        for (int i = 0; i < 2; ++i) {
            int s = tid + i * NTHR;
            int mt = s >> 6, ln = s & 63;
            int row = mt * 16 + (ln & 15);
            int c0 = (ln >> 4) * 8;
            ushort tb[8];
            #pragma unroll
            for (int j = 0; j < 8; ++j) tb[j] = rhd_s[row * RLS + c0 + j];
            *(s16x8*)&rhc[((mt * 16 + rank) * 64 + ln) * 8] = *(s16x8*)tb;
        }
        cluster_bar(cnt, (unsigned int)(RANKS * (2 * t + 2)));

        // ---- GEMM2: h~ = (r*hd) x Wh (512x32) ----
        f32x4 acc2[2][2];
        #pragma unroll
        for (int mt = 0; mt < 2; ++mt)
            #pragma unroll
            for (int nt = 0; nt < 2; ++nt) acc2[mt][nt] = (f32x4){0,0,0,0};
        #pragma unroll
        for (int kt = 0; kt < 16; ++kt) {
            s16x8 a0 = RH[((2 * wv    ) * 16 + kt) * 64 + l];
            s16x8 a1 = RH[((2 * wv + 1) * 16 + kt) * 64 + l];
            #pragma unroll
            for (int nt = 0; nt < 2; ++nt) {
                s16x8 bh_ = WF[(64 + nt * 16 + kt) * 64 + l];
                acc2[0][nt] = __builtin_amdgcn_mfma_f32_16x16x32_bf16(a0, bh_, acc2[0][nt], 0, 0, 0);
                acc2[1][nt] = __builtin_amdgcn_mfma_f32_16x16x32_bf16(a1, bh_, acc2[1][nt], 0, 0, 0);
            }
        }
        // ---- h~ epilogue + fused state update (all local) ----
        #pragma unroll
        for (int mt = 0; mt < 2; ++mt) {
            #pragma unroll
            for (int nt = 0; nt < 2; ++nt) {
                int c = nt * 16 + colb;
                float4 eh = epi_s[64 + c];
                #pragma unroll
                for (int q = 0; q < 4; ++q) {
                    int row = wv * 32 + mt * 16 + qg * 4 + q;
                    float ht = tanh_f(acc2[mt][nt][q] + eh.x + xi_s[row] * eh.y + mts_s[row] * eh.z);
                    float hd = h_lds[row * HLS + c];
                    h_lds[row * HLS + c] = hd + zq[mt][nt][q] * (ht - hd);
                }
            }
        }
        __syncthreads();   // protect xi_s/h_lds before next step's overwrite
    }

    // ---- output head: partial dot over own 32 cols, deterministic cross-rank sum ----
    if (tid < CROWS) {
        float s = 0.f;
        #pragma unroll
        for (int c = 0; c < OWNC; ++c) s += h_lds[tid * HLS + c] * Wo[rank * OWNC + c];
        osum[(size_t)(r0 + tid) * RANKS + rank] = s;
    }
    cluster_bar(cnt, (unsigned int)(RANKS * (2 * T_LEN + 1)));
    if (rank == 0 && tid < CROWS) {
        float s = 0.f;
        #pragma unroll
        for (int rk = 0; rk < RANKS; ++rk) s += osum[(size_t)(r0 + tid) * RANKS + rk];
        out[r0 + tid] = sigmoid_f(s + bo[0]);
    }
}

extern "C" void kernel_launch(void* const* d_in, const int* in_sizes, int n_in,
                              void* d_out, int out_size, void* d_ws, size_t ws_size,
                              hipStream_t stream) {
    const float* x    = (const float*)d_in[0];
    const float* xl   = (const float*)d_in[1];
    const float* itv  = (const float*)d_in[2];
    const float* msk  = (const float*)d_in[3];
    const float* Wgx  = (const float*)d_in[4];
    const float* bgx  = (const float*)d_in[5];
    const float* Wgh  = (const float*)d_in[6];
    const float* bgh  = (const float*)d_in[7];
    const float* Wz   = (const float*)d_in[8];
    const float* bz   = (const float*)d_in[9];
    const float* Wr   = (const float*)d_in[10];
    const float* br   = (const float*)d_in[11];
    const float* Wh   = (const float*)d_in[12];
    const float* bh   = (const float*)d_in[13];
    const float* Wo   = (const float*)d_in[14];
    const float* bo   = (const float*)d_in[15];

    char* ws = (char*)d_ws;
    float*        xmean = (float*)ws;                          // 16384 B
    unsigned int* barc  = (unsigned int*)(ws + 16384);         // 16*256 B = 4096 B
    float*        osum  = (float*)(ws + 16384 + 4096);         // 4096*16*4 = 262144 B
    ushort*       hdx   = (ushort*)(ws + 16384 + 4096 + 262144);            // 4 MB
    ushort*       rhx   = (ushort*)(ws + 16384 + 4096 + 262144 + 4194304);  // 4 MB

    k_init<<<1, 1024, 0, stream>>>(barc);
    k_xmean<<<B_TOT, 64, 0, stream>>>(x, msk, xmean);
    k_grud<<<CLUSTERS * RANKS, NTHR, 0, stream>>>(
        x, xl, itv, msk, Wgx, bgx, Wgh, bgh,
        Wz, bz, Wr, br, Wh, bh, Wo, bo,
        xmean, hdx, rhx, osum, barc, (float*)d_out);
}

// Round 8
// 6982.364 us; speedup vs baseline: 7.6256x; 2.1232x over previous
//
#include <hip/hip_runtime.h>
#include <stdint.h>

#define T_LEN 512
#define H_DIM 512
#define B_TOT 4096
#define GATE_D 514
#define CLUSTERS 16
#define RANKS 16        // blocks per cluster
#define CROWS 256       // batch rows per cluster
#define OWNC 32         // h-columns owned per block
#define NTHR 512        // 8 waves
#define HLS 33          // h_lds row stride (f32, padded)
#define RLS 34          // rhd_s row stride (ushort, padded)
#define BARPAD 64       // uints between cluster counters (256B)

typedef short s16x8 __attribute__((ext_vector_type(8)));
typedef float f32x4 __attribute__((ext_vector_type(4)));

__device__ __forceinline__ ushort f2bf(float f) {
    uint32_t u = __builtin_bit_cast(uint32_t, f);
    u += 0x7FFF + ((u >> 16) & 1);     // RNE
    return (ushort)(u >> 16);
}
__device__ __forceinline__ float sigmoid_f(float x) {
    return 1.0f / (1.0f + __expf(-x));
}
__device__ __forceinline__ float tanh_f(float x) {
    float ax = fabsf(x);
    float e  = __expf(2.0f * ax);
    float t  = 1.0f - 2.0f / (e + 1.0f);
    return copysignf(t, x);
}
__device__ __forceinline__ void vm0() {
    asm volatile("s_waitcnt vmcnt(0)" ::: "memory");
}

// ---------------- K0: masked mean over time ----------------
__global__ void k_xmean(const float* __restrict__ x, const float* __restrict__ m,
                        float* __restrict__ xmean) {
    int b = blockIdx.x;
    int l = threadIdx.x;
    const float* xr = x + (size_t)b * T_LEN;
    const float* mr = m + (size_t)b * T_LEN;
    float sx = 0.f, sm = 0.f;
    #pragma unroll
    for (int i = 0; i < T_LEN / 64; ++i) {
        float mv = mr[l + i * 64];
        sx += xr[l + i * 64] * mv;
        sm += mv;
    }
    for (int off = 32; off; off >>= 1) {
        sx += __shfl_down(sx, off);
        sm += __shfl_down(sm, off);
    }
    if (l == 0) xmean[b] = sx / sm;
}

// ---------------- K_init: zero padded cluster barrier slots ----------------
__global__ void k_init(unsigned int* barc) {
    int i = threadIdx.x + blockIdx.x * blockDim.x;
    if (i < CLUSTERS * BARPAD) barc[i] = 0u;
}

// ---------------- fenced (cross-XCD-safe) cluster barrier — round-4 proven ----------------
__device__ __forceinline__ void bar_slow(unsigned int* cnt, unsigned int target) {
    vm0();
    __syncthreads();
    if (threadIdx.x == 0) {
        __builtin_amdgcn_fence(__ATOMIC_RELEASE, "agent");
        __hip_atomic_fetch_add(cnt, 1u, __ATOMIC_RELAXED, __HIP_MEMORY_SCOPE_AGENT);
        while (__hip_atomic_load(cnt, __ATOMIC_RELAXED, __HIP_MEMORY_SCOPE_AGENT) < target)
            __builtin_amdgcn_s_sleep(1);
        __builtin_amdgcn_fence(__ATOMIC_ACQUIRE, "agent");
    }
    __syncthreads();
}

// ---------------- same-XCD cluster barrier ----------------
// Valid only when all 16 blocks share one XCD (runtime-verified).
// CDNA vector L1 is WRITE-THROUGH: plain stores reach the shared L2 once vmcnt
// drains (done before s_barrier). So release needs NO wbl2; acquire needs only a
// per-CU L1 flash-invalidate (buffer_inv — the gfx90a __threadfence protocol).
// Arrival/poll use the proven compiler-generated relaxed agent-scope atomics.
__device__ __forceinline__ void bar_fast(unsigned int* cnt, unsigned int target) {
    vm0();
    __syncthreads();
    if (threadIdx.x == 0) {
        __hip_atomic_fetch_add(cnt, 1u, __ATOMIC_RELAXED, __HIP_MEMORY_SCOPE_AGENT);
        while (__hip_atomic_load(cnt, __ATOMIC_RELAXED, __HIP_MEMORY_SCOPE_AGENT) < target)
            __builtin_amdgcn_s_sleep(1);
        asm volatile("buffer_inv" ::: "memory");   // L1-only invalidate (block = 1 CU)
        vm0();                                     // inv retired before barrier release
    }
    __syncthreads();
}

// ---------------- main persistent kernel ----------------
// 256 blocks x 512 threads. Cluster = 16 blocks sharing 256 batch rows; the b%8
// mapping targets one XCD per cluster, VERIFIED at runtime via HW_REG_XCC_ID.
// Verified clusters sync with the L1-inv-only barrier; others use the fenced one.
__global__ __launch_bounds__(NTHR, 2) void k_grud(
    const float* __restrict__ x,   const float* __restrict__ xl,
    const float* __restrict__ itv, const float* __restrict__ msk,
    const float* __restrict__ Wgx, const float* __restrict__ bgx,
    const float* __restrict__ Wgh, const float* __restrict__ bgh,
    const float* __restrict__ Wz,  const float* __restrict__ bz,
    const float* __restrict__ Wr,  const float* __restrict__ br,
    const float* __restrict__ Wh,  const float* __restrict__ bh,
    const float* __restrict__ Wo,  const float* __restrict__ bo,
    const float* __restrict__ xmean,
    ushort* __restrict__ hdx, ushort* __restrict__ rhx,
    float* __restrict__ osum, unsigned int* __restrict__ barc,
    float* __restrict__ out)
{
    __shared__ ushort wfrag[96 * 512];        // 98304 B  weight B-fragments (z:0-31, r:32-63, h:64-95)
    __shared__ float  h_lds[CROWS * HLS];     // 33792 B  fp32 state / hd (own 32 cols)
    __shared__ ushort rhd_s[CROWS * RLS];     // 17408 B  r*hd staging (bf16)
    __shared__ float  xi_s[CROWS], mts_s[CROWS], its_s[CROWS];  // 3072 B
    __shared__ float4 epi_s[96];              // 1536 B   {bias, W[:,0], W[:,513]} per gate/own col
    __shared__ float2 ghb_s[OWNC];            // 256 B
    __shared__ unsigned int flag_s;

    const int tid = threadIdx.x;
    const int b   = blockIdx.x;
    const int cluster = (b & 7) * 2 + ((b >> 3) >> 4);   // same-XCD grouping heuristic
    const int rank    = (b >> 3) & 15;
    const int wv = tid >> 6, l = tid & 63;
    const int colb = l & 15, qg = l >> 4;
    const int r0 = cluster * CROWS;

    unsigned int* cnt     = barc + cluster * BARPAD;   // line 0 of the 256B slot
    unsigned int* xcd_arr = cnt + 16;                  // line 1: per-rank XCC ids
    ushort* hdc = hdx + (size_t)cluster * CROWS * H_DIM;
    ushort* rhc = rhx + (size_t)cluster * CROWS * H_DIM;
    const s16x8* WF = (const s16x8*)wfrag;
    const s16x8* HD = (const s16x8*)hdc;
    const s16x8* RH = (const s16x8*)rhc;

    // ---- one-time init: state, weight fragments, epilogue tables ----
    for (int i = tid; i < CROWS * HLS; i += NTHR) h_lds[i] = 0.f;
    for (int s = tid; s < 96 * 64; s += NTHR) {
        int fi = s >> 6, ln = s & 63;
        int g = fi >> 5, nt = (fi >> 4) & 1, kt = fi & 15;
        const float* W = (g == 0) ? Wz : (g == 1) ? Wr : Wh;
        int colg = rank * OWNC + nt * 16 + (ln & 15);
        int c0 = 1 + kt * 32 + (ln >> 4) * 8;
        ushort tb[8];
        #pragma unroll
        for (int j = 0; j < 8; ++j) tb[j] = f2bf(W[(size_t)colg * GATE_D + c0 + j]);
        *(s16x8*)&wfrag[s * 8] = *(s16x8*)tb;
    }
    for (int i = tid; i < 96; i += NTHR) {
        int g = i >> 5, c = i & 31;
        const float* W  = (g == 0) ? Wz : (g == 1) ? Wr : Wh;
        const float* bb = (g == 0) ? bz : (g == 1) ? br : bh;
        int colg = rank * OWNC + c;
        epi_s[i] = make_float4(bb[colg], W[(size_t)colg * GATE_D],
                               W[(size_t)colg * GATE_D + GATE_D - 1], 0.f);
    }
    if (tid < OWNC) ghb_s[tid] = make_float2(Wgh[rank * OWNC + tid], bgh[rank * OWNC + tid]);
    const float wgx = Wgx[0], bgx0 = bgx[0];

    // ---- registration: publish XCC_ID, fenced barrier, verify cluster uniformity ----
    if (tid == 0) {
        unsigned int myxcc;
        asm volatile("s_getreg_b32 %0, hwreg(HW_REG_XCC_ID)" : "=s"(myxcc));
        xcd_arr[rank] = myxcc;                 // plain store; flushed by bar_slow release
    }
    unsigned int ep = 1;
    bar_slow(cnt, RANKS * ep);                 // epoch 1 (fenced both sides)
    if (tid == 0) {
        unsigned int x0 = xcd_arr[0], same = 1;
        #pragma unroll
        for (int rk = 1; rk < RANKS; ++rk) same &= (xcd_arr[rk] == x0) ? 1u : 0u;
        flag_s = same;
    }
    __syncthreads();
    const bool fastc = (flag_s != 0);

    float zq[2][2][4];

    for (int t = 0; t < T_LEN; ++t) {
        // ---- per-row scalars ----
        if (tid < CROWS) {
            size_t idx = (size_t)(r0 + tid) * T_LEN + t;
            float xv = x[idx], xlv = xl[idx], iv = itv[idx], mv = msk[idx];
            float gx = __expf(-fmaxf(iv * wgx + bgx0, 0.f));
            xi_s[tid]  = mv * xv + (1.f - mv) * (gx * xlv + (1.f - gx) * xmean[r0 + tid]);
            mts_s[tid] = mv;
            its_s[tid] = iv;
        }
        __syncthreads();

        // ---- phase 1: hd = gamma_h * h (fp32 in place) + bf16 frag -> hdx (kt = rank) ----
        #pragma unroll
        for (int i = 0; i < 2; ++i) {
            int s = tid + i * NTHR;            // 0..1023: (mt 0..15, ln 0..63)
            int mt = s >> 6, ln = s & 63;
            int row = mt * 16 + (ln & 15);
            int c0 = (ln >> 4) * 8;
            float it = its_s[row];
            float hv[8]; ushort tb[8];
            #pragma unroll
            for (int j = 0; j < 8; ++j) {
                float2 gb = ghb_s[c0 + j];
                float g  = __expf(-fmaxf(it * gb.x + gb.y, 0.f));
                float hd = h_lds[row * HLS + c0 + j] * g;
                hv[j] = hd; tb[j] = f2bf(hd);
            }
            #pragma unroll
            for (int j = 0; j < 8; ++j) h_lds[row * HLS + c0 + j] = hv[j];
            *(s16x8*)&hdc[((mt * 16 + rank) * 64 + ln) * 8] = *(s16x8*)tb;
        }
        ++ep;
        if (fastc) bar_fast(cnt, RANKS * ep); else bar_slow(cnt, RANKS * ep);

        // ---- GEMM1: z,r = hd (256x512) x W (512x64), wave rows [32wv, 32wv+32) ----
        f32x4 accz[2][2], accr[2][2];
        #pragma unroll
        for (int mt = 0; mt < 2; ++mt)
            #pragma unroll
            for (int nt = 0; nt < 2; ++nt) { accz[mt][nt] = (f32x4){0,0,0,0}; accr[mt][nt] = (f32x4){0,0,0,0}; }
        #pragma unroll
        for (int kt = 0; kt < 16; ++kt) {
            s16x8 a0 = HD[((2 * wv    ) * 16 + kt) * 64 + l];
            s16x8 a1 = HD[((2 * wv + 1) * 16 + kt) * 64 + l];
            #pragma unroll
            for (int nt = 0; nt < 2; ++nt) {
                s16x8 bz_ = WF[(     nt * 16 + kt) * 64 + l];
                s16x8 br_ = WF[(32 + nt * 16 + kt) * 64 + l];
                accz[0][nt] = __builtin_amdgcn_mfma_f32_16x16x32_bf16(a0, bz_, accz[0][nt], 0, 0, 0);
                accz[1][nt] = __builtin_amdgcn_mfma_f32_16x16x32_bf16(a1, bz_, accz[1][nt], 0, 0, 0);
                accr[0][nt] = __builtin_amdgcn_mfma_f32_16x16x32_bf16(a0, br_, accr[0][nt], 0, 0, 0);
                accr[1][nt] = __builtin_amdgcn_mfma_f32_16x16x32_bf16(a1, br_, accr[1][nt], 0, 0, 0);
            }
        }
        // ---- z,r epilogue: z -> regs, r*hd -> rhd_s ----
        #pragma unroll
        for (int mt = 0; mt < 2; ++mt) {
            #pragma unroll
            for (int nt = 0; nt < 2; ++nt) {
                int c = nt * 16 + colb;
                float4 ez = epi_s[c];
                float4 er = epi_s[32 + c];
                #pragma unroll
                for (int q = 0; q < 4; ++q) {
                    int row = wv * 32 + mt * 16 + qg * 4 + q;
                    float xiv = xi_s[row], mtv = mts_s[row];
                    zq[mt][nt][q] = sigmoid_f(accz[mt][nt][q] + ez.x + xiv * ez.y + mtv * ez.z);
                    float rr = sigmoid_f(accr[mt][nt][q] + er.x + xiv * er.y + mtv * er.z);
                    float hd = h_lds[row * HLS + c];
                    rhd_s[row * RLS + c] = f2bf(rr * hd);
                }
            }
        }
        __syncthreads();
        // ---- frag-copy rhd_s -> rhx (kt = rank) ----
        #pragma unroll
        for (int i = 0; i < 2; ++i) {
            int s = tid + i * NTHR;
            int mt = s >> 6, ln = s & 63;
            int row = mt * 16 + (ln & 15);
            int c0 = (ln >> 4) * 8;
            ushort tb[8];
            #pragma unroll
            for (int j = 0; j < 8; ++j) tb[j] = rhd_s[row * RLS + c0 + j];
            *(s16x8*)&rhc[((mt * 16 + rank) * 64 + ln) * 8] = *(s16x8*)tb;
        }
        ++ep;
        if (fastc) bar_fast(cnt, RANKS * ep); else bar_slow(cnt, RANKS * ep);

        // ---- GEMM2: h~ = (r*hd) x Wh (512x32) ----
        f32x4 acc2[2][2];
        #pragma unroll
        for (int mt = 0; mt < 2; ++mt)
            #pragma unroll
            for (int nt = 0; nt < 2; ++nt) acc2[mt][nt] = (f32x4){0,0,0,0};
        #pragma unroll
        for (int kt = 0; kt < 16; ++kt) {
            s16x8 a0 = RH[((2 * wv    ) * 16 + kt) * 64 + l];
            s16x8 a1 = RH[((2 * wv + 1) * 16 + kt) * 64 + l];
            #pragma unroll
            for (int nt = 0; nt < 2; ++nt) {
                s16x8 bh_ = WF[(64 + nt * 16 + kt) * 64 + l];
                acc2[0][nt] = __builtin_amdgcn_mfma_f32_16x16x32_bf16(a0, bh_, acc2[0][nt], 0, 0, 0);
                acc2[1][nt] = __builtin_amdgcn_mfma_f32_16x16x32_bf16(a1, bh_, acc2[1][nt], 0, 0, 0);
            }
        }
        // ---- h~ epilogue + fused state update (all local) ----
        #pragma unroll
        for (int mt = 0; mt < 2; ++mt) {
            #pragma unroll
            for (int nt = 0; nt < 2; ++nt) {
                int c = nt * 16 + colb;
                float4 eh = epi_s[64 + c];
                #pragma unroll
                for (int q = 0; q < 4; ++q) {
                    int row = wv * 32 + mt * 16 + qg * 4 + q;
                    float ht = tanh_f(acc2[mt][nt][q] + eh.x + xi_s[row] * eh.y + mts_s[row] * eh.z);
                    float hd = h_lds[row * HLS + c];
                    h_lds[row * HLS + c] = hd + zq[mt][nt][q] * (ht - hd);
                }
            }
        }
        __syncthreads();   // protect xi_s/h_lds before next step's overwrite
    }

    // ---- output head: partial dot over own 32 cols, deterministic cross-rank sum ----
    if (tid < CROWS) {
        float s = 0.f;
        #pragma unroll
        for (int c = 0; c < OWNC; ++c) s += h_lds[tid * HLS + c] * Wo[rank * OWNC + c];
        osum[(size_t)(r0 + tid) * RANKS + rank] = s;
    }
    ++ep;
    if (fastc) bar_fast(cnt, RANKS * ep); else bar_slow(cnt, RANKS * ep);
    if (rank == 0 && tid < CROWS) {
        float s = 0.f;
        #pragma unroll
        for (int rk = 0; rk < RANKS; ++rk) s += osum[(size_t)(r0 + tid) * RANKS + rk];
        out[r0 + tid] = sigmoid_f(s + bo[0]);
    }
}

extern "C" void kernel_launch(void* const* d_in, const int* in_sizes, int n_in,
                              void* d_out, int out_size, void* d_ws, size_t ws_size,
                              hipStream_t stream) {
    const float* x    = (const float*)d_in[0];
    const float* xl   = (const float*)d_in[1];
    const float* itv  = (const float*)d_in[2];
    const float* msk  = (const float*)d_in[3];
    const float* Wgx  = (const float*)d_in[4];
    const float* bgx  = (const float*)d_in[5];
    const float* Wgh  = (const float*)d_in[6];
    const float* bgh  = (const float*)d_in[7];
    const float* Wz   = (const float*)d_in[8];
    const float* bz   = (const float*)d_in[9];
    const float* Wr   = (const float*)d_in[10];
    const float* br   = (const float*)d_in[11];
    const float* Wh   = (const float*)d_in[12];
    const float* bh   = (const float*)d_in[13];
    const float* Wo   = (const float*)d_in[14];
    const float* bo   = (const float*)d_in[15];

    char* ws = (char*)d_ws;
    float*        xmean = (float*)ws;                          // 16384 B
    unsigned int* barc  = (unsigned int*)(ws + 16384);         // 16*256 B (counter + xcd slots)
    float*        osum  = (float*)(ws + 16384 + 4096);         // 262144 B
    ushort*       hdx   = (ushort*)(ws + 16384 + 4096 + 262144);            // 4 MB
    ushort*       rhx   = (ushort*)(ws + 16384 + 4096 + 262144 + 4194304);  // 4 MB

    k_init<<<1, 1024, 0, stream>>>(barc);
    k_xmean<<<B_TOT, 64, 0, stream>>>(x, msk, xmean);
    k_grud<<<CLUSTERS * RANKS, NTHR, 0, stream>>>(
        x, xl, itv, msk, Wgx, bgx, Wgh, bgh,
        Wz, bz, Wr, br, Wh, bh, Wo, bo,
        xmean, hdx, rhx, osum, barc, (float*)d_out);
}